// Round 1
// 464.216 us; speedup vs baseline: 1.1031x; 1.1031x over previous
//
#include <hip/hip_runtime.h>
#include <cstdint>

typedef uint16_t u16;
typedef uint32_t u32;
typedef uint64_t u64;
typedef __attribute__((ext_vector_type(4))) float f32x4;
typedef __attribute__((ext_vector_type(8))) short bf16x8;

__device__ __forceinline__ u16 f2bf(float f) {
  union { float f; u32 i; } u; u.f = f;
  u32 r = u.i + 0x7FFFu + ((u.i >> 16) & 1u);
  return (u16)(r >> 16);
}
__device__ __forceinline__ float sigm(float x) { return 1.f / (1.f + __expf(-x)); }

// ---------------- K0: pre-pack fin_w f32 -> bf16 (GEMM B operand) --------
__global__ __launch_bounds__(256) void k0_pack(
    const float* __restrict__ fw, u16* __restrict__ fwb)
{
  int i = blockIdx.x * 256 + threadIdx.x;
  f32x4 v = ((const f32x4*)fw)[i];
  u64 p = (u64)f2bf(v[0]) | ((u64)f2bf(v[1]) << 16) |
          ((u64)f2bf(v[2]) << 32) | ((u64)f2bf(v[3]) << 48);
  ((u64*)fwb)[i] = p;
}

// ---------------- K1: r = relu(bn(conv1x1(gate))) , fp32 out -------------
__global__ __launch_bounds__(256) void k1_reduce(
    const float* __restrict__ x, const float* __restrict__ rw, const float* __restrict__ rb,
    const float* __restrict__ bg, const float* __restrict__ bb, const float* __restrict__ bm,
    const float* __restrict__ bv, float* __restrict__ r)
{
  __shared__ __align__(16) float wl[256][16];
  __shared__ float bl[16];
  __shared__ float sl[16];
  int t = threadIdx.x;
  if (t < 16) {
    float s = bg[t] * rsqrtf(bv[t] + 1e-5f);
    sl[t] = s;
    bl[t] = (rb[t] - bm[t]) * s + bb[t];
  }
  __syncthreads();
  for (int i = 0; i < 16; ++i) {
    int flat = i * 256 + t;
    int co = flat >> 8, c = flat & 255;
    wl[c][co] = rw[co * 256 + c] * sl[co];
  }
  __syncthreads();
  int p = blockIdx.x * 256 + t;
  int b = p >> 12, pp = p & 4095;
  const float* gsrc = x + ((size_t)(b * 512 + 256)) * 4096 + pp;
  float acc[16];
#pragma unroll
  for (int co = 0; co < 16; ++co) acc[co] = bl[co];
#pragma unroll 4
  for (int c = 0; c < 256; ++c) {
    float g = gsrc[(size_t)c * 4096];
    const f32x4* wr = (const f32x4*)(&wl[c][0]);
    f32x4 a0 = wr[0], a1 = wr[1], a2 = wr[2], a3 = wr[3];
    acc[0]  += g * a0[0]; acc[1]  += g * a0[1]; acc[2]  += g * a0[2]; acc[3]  += g * a0[3];
    acc[4]  += g * a1[0]; acc[5]  += g * a1[1]; acc[6]  += g * a1[2]; acc[7]  += g * a1[3];
    acc[8]  += g * a2[0]; acc[9]  += g * a2[1]; acc[10] += g * a2[2]; acc[11] += g * a2[3];
    acc[12] += g * a3[0]; acc[13] += g * a3[1]; acc[14] += g * a3[2]; acc[15] += g * a3[3];
  }
  float* rd = r + ((size_t)b * 16) * 4096 + pp;
#pragma unroll
  for (int co = 0; co < 16; ++co) rd[(size_t)co * 4096] = fmaxf(acc[co], 0.f);
}

// ---------------- K2: means over h / w / both (LDS-staged) ---------------
// grid 256 (b*16+c) x 256 thr
__global__ __launch_bounds__(256) void k2_means(
    const float* __restrict__ r, float* __restrict__ cm, float* __restrict__ rm,
    float* __restrict__ ctx)
{
  __shared__ __align__(16) float tile[64][68];
  int bc = blockIdx.x, t = threadIdx.x;
  const float* src = r + (size_t)bc * 4096;
#pragma unroll
  for (int i = 0; i < 4; ++i) {
    int off = (i * 256 + t) * 4;
    int row = off >> 6, col = off & 63;
    f32x4 v = *(const f32x4*)(src + off);
    *(f32x4*)&tile[row][col] = v;
  }
  __syncthreads();
  int wv = t >> 6, lane = t & 63;
  if (wv == 0) {
    float s = 0.f;
    for (int h = 0; h < 64; ++h) s += tile[h][lane];
    cm[bc * 64 + lane] = s * (1.f / 64.f);
    float tot = s;
#pragma unroll
    for (int m = 32; m; m >>= 1) tot += __shfl_xor(tot, m, 64);
    if (lane == 0) ctx[bc] = tot * (1.f / 4096.f);
  } else if (wv == 1) {
    float s = 0.f;
    for (int w0 = 0; w0 < 64; ++w0) s += tile[lane][(w0 + lane) & 63];
    rm[bc * 64 + lane] = s * (1.f / 64.f);
  }
}

// ---------------- K3a: gct weights + attn (DWT path collapses to ctx) ----
__global__ __launch_bounds__(256) void k3a_gct(
    const float* __restrict__ ctx,
    const float* f1w, const float* f1b, const float* lng, const float* lnb,
    const float* f2w, const float* f2b, const float* fcw, const float* fcb,
    float* __restrict__ wgct, float* __restrict__ attn)
{
  __shared__ float cl[256];
  __shared__ float gl[256];
  int t = threadIdx.x;
  cl[t] = ctx[t];
  __syncthreads();
  int b = t >> 4, c = t & 15;
  const float* cb = &cl[b * 16];
  float a[4];
#pragma unroll
  for (int j = 0; j < 4; ++j) {
    float s = f1b[j];
    for (int i = 0; i < 16; ++i) s += cb[i] * f1w[j * 16 + i];
    a[j] = s;
  }
  float mu = 0.25f * (a[0] + a[1] + a[2] + a[3]);
  float var = 0.f;
#pragma unroll
  for (int j = 0; j < 4; ++j) { float d = a[j] - mu; var += d * d; }
  var *= 0.25f;
  float inv = rsqrtf(var + 1e-5f);
#pragma unroll
  for (int j = 0; j < 4; ++j)
    a[j] = fmaxf((a[j] - mu) * inv * lng[j] + lnb[j], 0.f);
  float s2 = f2b[c];
#pragma unroll
  for (int j = 0; j < 4; ++j) s2 += a[j] * f2w[c * 4 + j];
  wgct[t] = sigm(s2);
  float g = fcb[c];
  for (int i = 0; i < 16; ++i) g += cb[i] * fcw[c * 16 + i];
  gl[t] = g;
  __syncthreads();
  const float* gb = &gl[b * 16];
  float mx = -1e30f;
  for (int i = 0; i < 16; ++i) mx = fmaxf(mx, gb[i]);
  float den = 0.f;
  for (int i = 0; i < 16; ++i) den += __expf(gb[i] - mx);
  attn[t] = __expf(g - mx) / den;
}

// ---------------- K3b: rel h/v 1D convs -> hfc[b,o,w], vfc[b,o,h] --------
__global__ __launch_bounds__(64) void k3b_rel(
    const float* __restrict__ cm, const float* __restrict__ rm,
    const float* hw, const float* hb, const float* hbg, const float* hbb, const float* hbm, const float* hbv,
    const float* vw, const float* vb_, const float* vbg, const float* vbb, const float* vbm, const float* vbv,
    const float* fw, const float* fb, float* __restrict__ hfc, float* __restrict__ vfc)
{
  __shared__ float cml[16][64], rml[16][64];
  int b = blockIdx.x, t = threadIdx.x;
  for (int i = 0; i < 16; ++i) {
    cml[i][t] = cm[(b * 16 + i) * 64 + t];
    rml[i][t] = rm[(b * 16 + i) * 64 + t];
  }
  __syncthreads();
  float hf[8], vf[8];
  for (int o = 0; o < 8; ++o) {
    float sh = 0.f, sv = 0.f;
    for (int ci = 0; ci < 16; ++ci) {
#pragma unroll
      for (int kk = 0; kk < 3; ++kk) {
        int q = t + kk - 1;
        bool ok = (q >= 0 && q < 64);
        int qi = ok ? q : 0;
        float xh = ok ? cml[ci][qi] : 0.f;
        float xv = ok ? rml[ci][qi] : 0.f;
        sh += hw[(o * 16 + ci) * 3 + kk] * xh;
        sv += vw[(o * 16 + ci) * 3 + kk] * xv;
      }
    }
    float s1 = hbg[o] * rsqrtf(hbv[o] + 1e-5f);
    hf[o] = fmaxf((sh + hb[o] - hbm[o]) * s1 + hbb[o], 0.f);
    float s2 = vbg[o] * rsqrtf(vbv[o] + 1e-5f);
    vf[o] = fmaxf((sv + vb_[o] - vbm[o]) * s2 + vbb[o], 0.f);
  }
  for (int o = 0; o < 16; ++o) {
    float sh = fb[o], sv = 0.f;   // fus bias folded into hfc only
#pragma unroll
    for (int c = 0; c < 8; ++c) {
      sh += fw[o * 16 + c] * hf[c];
      sv += fw[o * 16 + 8 + c] * vf[c];
    }
    hfc[(b * 16 + o) * 64 + t] = sh;
    vfc[(b * 16 + o) * 64 + t] = sv;
  }
}

// ---------------- K4p: gate pipeline -> pack P[m][512] bf16 --------------
// grid 1024 (b*64+h) x 256 thr; LDS ~55 KB -> 2 blocks/CU
__global__ __launch_bounds__(256) void k4_pack(
    const float* __restrict__ x, const float* __restrict__ r,
    const float* __restrict__ wgct, const float* __restrict__ attn,
    const float* __restrict__ hfc, const float* __restrict__ vfc,
    const float* sfw, const float* sfb, const float* sg, const float* sb_,
    const float* sm, const float* sv, u16* __restrict__ P)
{
  __shared__ float inter[16][64];
  __shared__ __align__(16) float wsf[256][16];
  __shared__ float bsf[256];
  __shared__ float wg[16], at[16], vfh[16];
  __shared__ __align__(16) u16 t2[64][258];
  int bid = blockIdx.x;
  int b = bid >> 6, h = bid & 63;
  int t = threadIdx.x;

  // identity transpose f32 -> bf16 into t2[w][c]
  for (int i = 0; i < 16; ++i) {
    int flat = i * 256 + t;
    int c = flat >> 4, q = flat & 15;
    f32x4 v = *(const f32x4*)(x + ((size_t)(b * 512 + c)) * 4096 + h * 64 + q * 4);
#pragma unroll
    for (int j = 0; j < 4; ++j) t2[q * 4 + j][c] = f2bf(v[j]);
  }
  if (t < 16) {
    wg[t] = wgct[b * 16 + t];
    at[t] = attn[b * 16 + t];
    vfh[t] = vfc[(b * 16 + t) * 64 + h];
  }
  {
    int o = t;
    float s = sg[o] * rsqrtf(sv[o] + 1e-5f);
    bsf[o] = (sfb[o] - sm[o]) * s + sb_[o];
#pragma unroll
    for (int k2 = 0; k2 < 16; ++k2) wsf[o][k2] = sfw[o * 16 + k2] * s;
  }
  __syncthreads();
  // dump identity half: P[m][0..255]
  for (int i = 0; i < 32; ++i) {
    int flat = i * 256 + t;
    int wr = flat >> 7, cd = flat & 127;
    u32 d = *(const u32*)((const char*)t2 + wr * 516 + cd * 4);
    ((u32*)(P + ((size_t)(b * 4096 + h * 64 + wr)) * 512))[cd] = d;
  }
  // interaction[k][w]
  for (int i = 0; i < 4; ++i) {
    int idx = i * 256 + t;
    int k = idx >> 6, w = idx & 63;
    float rv = r[((size_t)(b * 16 + k)) * 4096 + h * 64 + w];
    float rel = sigm(hfc[(b * 16 + k) * 64 + w] + vfh[k]);
    inter[k][w] = rv * rv * wg[k] * rel + rv * at[k];
  }
  __syncthreads();
  // gated half -> t2[w][o]
  {
    int w = t & 63, og = t >> 6;
    float iv[16];
#pragma unroll
    for (int k2 = 0; k2 < 16; ++k2) iv[k2] = inter[k2][w];
    const float* gsrc = x + ((size_t)(b * 512 + 256)) * 4096 + h * 64 + w;
    for (int j = 0; j < 64; ++j) {
      int o = og * 64 + j;
      const f32x4* wr = (const f32x4*)(&wsf[o][0]);
      f32x4 w0 = wr[0], w1 = wr[1], w2 = wr[2], w3 = wr[3];
      float dot = bsf[o];
      dot += iv[0] * w0[0] + iv[1] * w0[1] + iv[2] * w0[2] + iv[3] * w0[3];
      dot += iv[4] * w1[0] + iv[5] * w1[1] + iv[6] * w1[2] + iv[7] * w1[3];
      dot += iv[8] * w2[0] + iv[9] * w2[1] + iv[10] * w2[2] + iv[11] * w2[3];
      dot += iv[12] * w3[0] + iv[13] * w3[1] + iv[14] * w3[2] + iv[15] * w3[3];
      float gwv = sigm(dot);
      float gv = gsrc[(size_t)o * 4096];
      t2[w][o] = f2bf(gv * gwv);
    }
  }
  __syncthreads();
  // dump gated half: P[m][256..511]
  for (int i = 0; i < 32; ++i) {
    int flat = i * 256 + t;
    int wr = flat >> 7, cd = flat & 127;
    u32 d = *(const u32*)((const char*)t2 + wr * 516 + cd * 4);
    ((u32*)(P + ((size_t)(b * 4096 + h * 64 + wr)) * 512 + 256))[cd] = d;
  }
}

// ---------------- K5: pure MFMA GEMM, A resident in LDS ------------------
// v2: 512 thr (8 waves), wave tile 64x64 -> acc[4][4]=64 VGPR, cap 128 VGPR
// => 4 waves/SIMD (16 waves/CU, 2 blocks/CU). Direct acc->global epilogue,
// zero Dsh, ONE barrier total. Same FETCH/WRITE; attacks latency stalls.
__global__ __launch_bounds__(512, 4) void k5_gemm(
    const u16* __restrict__ P, const u16* __restrict__ fwb,
    const float* __restrict__ fb, float* __restrict__ out)
{
  __shared__ __align__(16) u16 A[64 * 528];   // 67584 B, pitch 528 (conflict-free, measured 0)
  int bid = blockIdx.x;
  int b = bid >> 6, h = bid & 63;
  int t = threadIdx.x;
  int lane = t & 63, wv = t >> 6;
  int fr = lane & 15, quad = lane >> 4;

  // stage A: 4096 fragments of 16B, 8 per thread, coalesced
  const u16* Pb = P + (size_t)bid * 64 * 512;
#pragma unroll
  for (int i = 0; i < 8; ++i) {
    int f = i * 512 + t;
    int row = f >> 6, cf = f & 63;
    bf16x8 v = *(const bf16x8*)(Pb + (size_t)row * 512 + cf * 8);
    *(bf16x8*)(A + row * 528 + cf * 8) = v;
  }

  int n0w = wv * 64;
  f32x4 acc[4][4];
#pragma unroll
  for (int j = 0; j < 4; ++j) {
    float bvv = fb[n0w + j * 16 + fr];
    f32x4 b4 = {bvv, bvv, bvv, bvv};
#pragma unroll
    for (int i = 0; i < 4; ++i) acc[i][j] = b4;
  }
  __syncthreads();

  const u16* Bp = fwb + (size_t)(n0w + fr) * 512 + quad * 8;
  for (int kb = 0; kb < 16; ++kb) {
    int c0 = kb * 32 + quad * 8;
    bf16x8 af[4], bfr[4];
#pragma unroll
    for (int i = 0; i < 4; ++i)
      af[i] = *(const bf16x8*)(A + (i * 16 + fr) * 528 + c0);
#pragma unroll
    for (int j = 0; j < 4; ++j)
      bfr[j] = *(const bf16x8*)(Bp + (size_t)(j * 16) * 512 + kb * 32);
#pragma unroll
    for (int j = 0; j < 4; ++j)
#pragma unroll
      for (int i = 0; i < 4; ++i)
        acc[i][j] = __builtin_amdgcn_mfma_f32_16x16x32_bf16(af[i], bfr[j], acc[i][j], 0, 0, 0);
  }

  // direct epilogue: per (i,j) the 4 quads form a contiguous 64B segment;
  // i-loop covers 256B/row -> L2 write-combines to full lines. No barriers.
  float* ob = out + ((size_t)(b * 512 + n0w + fr)) * 4096 + h * 64 + quad * 4;
#pragma unroll
  for (int j = 0; j < 4; ++j)
#pragma unroll
    for (int i = 0; i < 4; ++i)
      *(f32x4*)(ob + (size_t)(j * 16) * 4096 + i * 16) = acc[i][j];
}

// ---------------- fallback: R5's fused kernel (passed; used if ws small) -
__global__ __launch_bounds__(256) void k45_fused(
    const float* __restrict__ x, const float* __restrict__ r,
    const float* __restrict__ wgct, const float* __restrict__ attn,
    const float* __restrict__ hfc, const float* __restrict__ vfc,
    const float* sfw, const float* sfb, const float* sg, const float* sb_,
    const float* sm, const float* sv,
    const u16* __restrict__ fwb, const float* __restrict__ fb,
    float* __restrict__ out)
{
  __shared__ __align__(16) char region0[67584];
  __shared__ __align__(16) float wsf[256][16];
  __shared__ float inter[16][64];
  __shared__ float bsf[256];
  __shared__ float wg[16], at[16], vfh[16];
  u16* A = (u16*)region0;
  float* Dsh = (float*)region0;

  int bid = blockIdx.x;
  int b = bid >> 6, h = bid & 63;
  int t = threadIdx.x;

  for (int i = 0; i < 16; ++i) {
    int flat = i * 256 + t;
    int c = flat >> 4, q = flat & 15;
    f32x4 v = *(const f32x4*)(x + ((size_t)(b * 512 + c)) * 4096 + h * 64 + q * 4);
#pragma unroll
    for (int j = 0; j < 4; ++j) A[(q * 4 + j) * 520 + c] = f2bf(v[j]);
  }
  if (t < 16) {
    wg[t] = wgct[b * 16 + t];
    at[t] = attn[b * 16 + t];
    vfh[t] = vfc[(b * 16 + t) * 64 + h];
  }
  {
    int o = t;
    float s = sg[o] * rsqrtf(sv[o] + 1e-5f);
    bsf[o] = (sfb[o] - sm[o]) * s + sb_[o];
#pragma unroll
    for (int k2 = 0; k2 < 16; ++k2) wsf[o][k2] = sfw[o * 16 + k2] * s;
  }
  __syncthreads();
  for (int i = 0; i < 4; ++i) {
    int idx = i * 256 + t;
    int k = idx >> 6, w = idx & 63;
    float rv = r[((size_t)(b * 16 + k)) * 4096 + h * 64 + w];
    float rel = sigm(hfc[(b * 16 + k) * 64 + w] + vfh[k]);
    inter[k][w] = rv * rv * wg[k] * rel + rv * at[k];
  }
  __syncthreads();
  {
    int w = t & 63, og = t >> 6;
    float iv[16];
#pragma unroll
    for (int k2 = 0; k2 < 16; ++k2) iv[k2] = inter[k2][w];
    const float* gsrc = x + ((size_t)(b * 512 + 256)) * 4096 + h * 64 + w;
    for (int j = 0; j < 64; ++j) {
      int o = og * 64 + j;
      const f32x4* wr = (const f32x4*)(&wsf[o][0]);
      f32x4 w0 = wr[0], w1 = wr[1], w2 = wr[2], w3 = wr[3];
      float dot = bsf[o];
      dot += iv[0] * w0[0] + iv[1] * w0[1] + iv[2] * w0[2] + iv[3] * w0[3];
      dot += iv[4] * w1[0] + iv[5] * w1[1] + iv[6] * w1[2] + iv[7] * w1[3];
      dot += iv[8] * w2[0] + iv[9] * w2[1] + iv[10] * w2[2] + iv[11] * w2[3];
      dot += iv[12] * w3[0] + iv[13] * w3[1] + iv[14] * w3[2] + iv[15] * w3[3];
      float gwv = sigm(dot);
      float gv = gsrc[(size_t)o * 4096];
      A[w * 520 + 256 + o] = f2bf(gv * gwv);
    }
  }
  __syncthreads();

  int lane = t & 63, wv = t >> 6;
  int fr = lane & 15, quad = lane >> 4;
  int n0w = wv * 128;
  f32x4 acc[4][8];
#pragma unroll
  for (int j = 0; j < 8; ++j) {
    float bvv = fb[n0w + j * 16 + fr];
    f32x4 b4 = {bvv, bvv, bvv, bvv};
#pragma unroll
    for (int i = 0; i < 4; ++i) acc[i][j] = b4;
  }
  for (int kb = 0; kb < 16; ++kb) {
    int c0 = kb * 32 + quad * 8;
    bf16x8 af[4];
#pragma unroll
    for (int i = 0; i < 4; ++i)
      af[i] = *(const bf16x8*)(A + (i * 16 + fr) * 520 + c0);
#pragma unroll
    for (int j = 0; j < 8; ++j) {
      bf16x8 bfr = *(const bf16x8*)(fwb + (size_t)(n0w + j * 16 + fr) * 512 + c0);
#pragma unroll
      for (int i = 0; i < 4; ++i)
        acc[i][j] = __builtin_amdgcn_mfma_f32_16x16x32_bf16(af[i], bfr, acc[i][j], 0, 0, 0);
    }
  }
  for (int half = 0; half < 2; ++half) {
    __syncthreads();
    if ((wv >> 1) == half) {
#pragma unroll
      for (int j = 0; j < 8; ++j) {
        int nl = n0w - half * 256 + j * 16 + fr;
#pragma unroll
        for (int i = 0; i < 4; ++i)
#pragma unroll
          for (int rg = 0; rg < 4; ++rg)
            Dsh[nl * 66 + i * 16 + quad * 4 + rg] = acc[i][j][rg];
      }
    }
    __syncthreads();
    for (int it = 0; it < 64; ++it) {
      int flat = it * 256 + t;
      int nl = flat >> 6, md = flat & 63;
      float d = Dsh[nl * 66 + md];
      out[((size_t)(b * 512 + half * 256 + nl)) * 4096 + h * 64 + md] = d;
    }
  }
}

extern "C" void kernel_launch(void* const* d_in, const int* in_sizes, int n_in,
                              void* d_out, int out_size, void* d_ws, size_t ws_size,
                              hipStream_t stream) {
  const float* x      = (const float*)d_in[0];
  const float* red_w  = (const float*)d_in[1];
  const float* red_b  = (const float*)d_in[2];
  const float* rbg    = (const float*)d_in[3];
  const float* rbb    = (const float*)d_in[4];
  const float* rbm    = (const float*)d_in[5];
  const float* rbv    = (const float*)d_in[6];
  const float* f1w    = (const float*)d_in[7];
  const float* f1b    = (const float*)d_in[8];
  const float* lng    = (const float*)d_in[9];
  const float* lnb    = (const float*)d_in[10];
  const float* f2w    = (const float*)d_in[11];
  const float* f2b    = (const float*)d_in[12];
  const float* rhw    = (const float*)d_in[13];
  const float* rhb    = (const float*)d_in[14];
  const float* rhbg   = (const float*)d_in[15];
  const float* rhbb   = (const float*)d_in[16];
  const float* rhbm   = (const float*)d_in[17];
  const float* rhbv   = (const float*)d_in[18];
  const float* rvw    = (const float*)d_in[19];
  const float* rvb    = (const float*)d_in[20];
  const float* rvbg   = (const float*)d_in[21];
  const float* rvbb   = (const float*)d_in[22];
  const float* rvbm   = (const float*)d_in[23];
  const float* rvbv   = (const float*)d_in[24];
  const float* fusw   = (const float*)d_in[25];
  const float* fusb   = (const float*)d_in[26];
  const float* fcw    = (const float*)d_in[29];
  const float* fcb    = (const float*)d_in[30];
  const float* sfw    = (const float*)d_in[31];
  const float* sfb    = (const float*)d_in[32];
  const float* sbg    = (const float*)d_in[33];
  const float* sbb    = (const float*)d_in[34];
  const float* sbm    = (const float*)d_in[35];
  const float* sbv    = (const float*)d_in[36];
  const float* finw   = (const float*)d_in[37];
  const float* finb   = (const float*)d_in[38];
  float* out = (float*)d_out;

  char* ws = (char*)d_ws;
  size_t off = 0;
  float* r   = (float*)(ws + off); off += (size_t)16 * 16 * 4096 * 4;   // 4 MB
  u16*   fwb = (u16*)(ws + off);   off += (size_t)512 * 512 * 2;        // 512 KB
  float* cm  = (float*)(ws + off); off += 65536;
  float* rm  = (float*)(ws + off); off += 65536;
  float* ctx = (float*)(ws + off); off += 1024;
  float* wg  = (float*)(ws + off); off += 1024;
  float* at  = (float*)(ws + off); off += 1024;
  float* hfc = (float*)(ws + off); off += 65536;
  float* vfc = (float*)(ws + off); off += 65536;
  u16*   P   = (u16*)(ws + off);
  size_t need = off + (size_t)65536 * 512 * 2;                          // +64 MB
  bool split = (ws_size >= need);

  k0_pack<<<256, 256, 0, stream>>>(finw, fwb);
  k1_reduce<<<256, 256, 0, stream>>>(x, red_w, red_b, rbg, rbb, rbm, rbv, r);
  k2_means<<<256, 256, 0, stream>>>(r, cm, rm, ctx);
  k3a_gct<<<1, 256, 0, stream>>>(ctx, f1w, f1b, lng, lnb, f2w, f2b, fcw, fcb, wg, at);
  k3b_rel<<<16, 64, 0, stream>>>(cm, rm, rhw, rhb, rhbg, rhbb, rhbm, rhbv,
                                 rvw, rvb, rvbg, rvbb, rvbm, rvbv, fusw, fusb, hfc, vfc);
  if (split) {
    k4_pack<<<1024, 256, 0, stream>>>(x, r, wg, at, hfc, vfc,
                                      sfw, sfb, sbg, sbb, sbm, sbv, P);
    k5_gemm<<<1024, 512, 0, stream>>>(P, fwb, finb, out);
  } else {
    k45_fused<<<1024, 256, 0, stream>>>(x, r, wg, at, hfc, vfc,
                                        sfw, sfb, sbg, sbb, sbm, sbv, fwb, finb, out);
  }
}

// Round 2
// 440.376 us; speedup vs baseline: 1.1628x; 1.0541x over previous
//
#include <hip/hip_runtime.h>
#include <cstdint>

typedef uint16_t u16;
typedef uint32_t u32;
typedef uint64_t u64;
typedef __attribute__((ext_vector_type(4))) float f32x4;
typedef __attribute__((ext_vector_type(8))) short bf16x8;

__device__ __forceinline__ u16 f2bf(float f) {
  union { float f; u32 i; } u; u.f = f;
  u32 r = u.i + 0x7FFFu + ((u.i >> 16) & 1u);
  return (u16)(r >> 16);
}
__device__ __forceinline__ float sigm(float x) { return 1.f / (1.f + __expf(-x)); }

// ---------------- K0: pre-pack fin_w f32 -> bf16 (GEMM B operand) --------
__global__ __launch_bounds__(256) void k0_pack(
    const float* __restrict__ fw, u16* __restrict__ fwb)
{
  int i = blockIdx.x * 256 + threadIdx.x;
  f32x4 v = ((const f32x4*)fw)[i];
  u64 p = (u64)f2bf(v[0]) | ((u64)f2bf(v[1]) << 16) |
          ((u64)f2bf(v[2]) << 32) | ((u64)f2bf(v[3]) << 48);
  ((u64*)fwb)[i] = p;
}

// ---------------- K1: r = relu(bn(conv1x1(gate))) , fp32 out -------------
__global__ __launch_bounds__(256) void k1_reduce(
    const float* __restrict__ x, const float* __restrict__ rw, const float* __restrict__ rb,
    const float* __restrict__ bg, const float* __restrict__ bb, const float* __restrict__ bm,
    const float* __restrict__ bv, float* __restrict__ r)
{
  __shared__ __align__(16) float wl[256][16];
  __shared__ float bl[16];
  __shared__ float sl[16];
  int t = threadIdx.x;
  if (t < 16) {
    float s = bg[t] * rsqrtf(bv[t] + 1e-5f);
    sl[t] = s;
    bl[t] = (rb[t] - bm[t]) * s + bb[t];
  }
  __syncthreads();
  for (int i = 0; i < 16; ++i) {
    int flat = i * 256 + t;
    int co = flat >> 8, c = flat & 255;
    wl[c][co] = rw[co * 256 + c] * sl[co];
  }
  __syncthreads();
  int p = blockIdx.x * 256 + t;
  int b = p >> 12, pp = p & 4095;
  const float* gsrc = x + ((size_t)(b * 512 + 256)) * 4096 + pp;
  float acc[16];
#pragma unroll
  for (int co = 0; co < 16; ++co) acc[co] = bl[co];
#pragma unroll 4
  for (int c = 0; c < 256; ++c) {
    float g = gsrc[(size_t)c * 4096];
    const f32x4* wr = (const f32x4*)(&wl[c][0]);
    f32x4 a0 = wr[0], a1 = wr[1], a2 = wr[2], a3 = wr[3];
    acc[0]  += g * a0[0]; acc[1]  += g * a0[1]; acc[2]  += g * a0[2]; acc[3]  += g * a0[3];
    acc[4]  += g * a1[0]; acc[5]  += g * a1[1]; acc[6]  += g * a1[2]; acc[7]  += g * a1[3];
    acc[8]  += g * a2[0]; acc[9]  += g * a2[1]; acc[10] += g * a2[2]; acc[11] += g * a2[3];
    acc[12] += g * a3[0]; acc[13] += g * a3[1]; acc[14] += g * a3[2]; acc[15] += g * a3[3];
  }
  float* rd = r + ((size_t)b * 16) * 4096 + pp;
#pragma unroll
  for (int co = 0; co < 16; ++co) rd[(size_t)co * 4096] = fmaxf(acc[co], 0.f);
}

// ---------------- K2: means over h / w / both (LDS-staged) ---------------
__global__ __launch_bounds__(256) void k2_means(
    const float* __restrict__ r, float* __restrict__ cm, float* __restrict__ rm,
    float* __restrict__ ctx)
{
  __shared__ __align__(16) float tile[64][68];
  int bc = blockIdx.x, t = threadIdx.x;
  const float* src = r + (size_t)bc * 4096;
#pragma unroll
  for (int i = 0; i < 4; ++i) {
    int off = (i * 256 + t) * 4;
    int row = off >> 6, col = off & 63;
    f32x4 v = *(const f32x4*)(src + off);
    *(f32x4*)&tile[row][col] = v;
  }
  __syncthreads();
  int wv = t >> 6, lane = t & 63;
  if (wv == 0) {
    float s = 0.f;
    for (int h = 0; h < 64; ++h) s += tile[h][lane];
    cm[bc * 64 + lane] = s * (1.f / 64.f);
    float tot = s;
#pragma unroll
    for (int m = 32; m; m >>= 1) tot += __shfl_xor(tot, m, 64);
    if (lane == 0) ctx[bc] = tot * (1.f / 4096.f);
  } else if (wv == 1) {
    float s = 0.f;
    for (int w0 = 0; w0 < 64; ++w0) s += tile[lane][(w0 + lane) & 63];
    rm[bc * 64 + lane] = s * (1.f / 64.f);
  }
}

// ---------------- K3a: gct weights + attn --------------------------------
__global__ __launch_bounds__(256) void k3a_gct(
    const float* __restrict__ ctx,
    const float* f1w, const float* f1b, const float* lng, const float* lnb,
    const float* f2w, const float* f2b, const float* fcw, const float* fcb,
    float* __restrict__ wgct, float* __restrict__ attn)
{
  __shared__ float cl[256];
  __shared__ float gl[256];
  int t = threadIdx.x;
  cl[t] = ctx[t];
  __syncthreads();
  int b = t >> 4, c = t & 15;
  const float* cb = &cl[b * 16];
  float a[4];
#pragma unroll
  for (int j = 0; j < 4; ++j) {
    float s = f1b[j];
    for (int i = 0; i < 16; ++i) s += cb[i] * f1w[j * 16 + i];
    a[j] = s;
  }
  float mu = 0.25f * (a[0] + a[1] + a[2] + a[3]);
  float var = 0.f;
#pragma unroll
  for (int j = 0; j < 4; ++j) { float d = a[j] - mu; var += d * d; }
  var *= 0.25f;
  float inv = rsqrtf(var + 1e-5f);
#pragma unroll
  for (int j = 0; j < 4; ++j)
    a[j] = fmaxf((a[j] - mu) * inv * lng[j] + lnb[j], 0.f);
  float s2 = f2b[c];
#pragma unroll
  for (int j = 0; j < 4; ++j) s2 += a[j] * f2w[c * 4 + j];
  wgct[t] = sigm(s2);
  float g = fcb[c];
  for (int i = 0; i < 16; ++i) g += cb[i] * fcw[c * 16 + i];
  gl[t] = g;
  __syncthreads();
  const float* gb = &gl[b * 16];
  float mx = -1e30f;
  for (int i = 0; i < 16; ++i) mx = fmaxf(mx, gb[i]);
  float den = 0.f;
  for (int i = 0; i < 16; ++i) den += __expf(gb[i] - mx);
  attn[t] = __expf(g - mx) / den;
}

// ---------------- K3b: rel h/v 1D convs ----------------------------------
__global__ __launch_bounds__(64) void k3b_rel(
    const float* __restrict__ cm, const float* __restrict__ rm,
    const float* hw, const float* hb, const float* hbg, const float* hbb, const float* hbm, const float* hbv,
    const float* vw, const float* vb_, const float* vbg, const float* vbb, const float* vbm, const float* vbv,
    const float* fw, const float* fb, float* __restrict__ hfc, float* __restrict__ vfc)
{
  __shared__ float cml[16][64], rml[16][64];
  int b = blockIdx.x, t = threadIdx.x;
  for (int i = 0; i < 16; ++i) {
    cml[i][t] = cm[(b * 16 + i) * 64 + t];
    rml[i][t] = rm[(b * 16 + i) * 64 + t];
  }
  __syncthreads();
  float hf[8], vf[8];
  for (int o = 0; o < 8; ++o) {
    float sh = 0.f, sv = 0.f;
    for (int ci = 0; ci < 16; ++ci) {
#pragma unroll
      for (int kk = 0; kk < 3; ++kk) {
        int q = t + kk - 1;
        bool ok = (q >= 0 && q < 64);
        int qi = ok ? q : 0;
        float xh = ok ? cml[ci][qi] : 0.f;
        float xv = ok ? rml[ci][qi] : 0.f;
        sh += hw[(o * 16 + ci) * 3 + kk] * xh;
        sv += vw[(o * 16 + ci) * 3 + kk] * xv;
      }
    }
    float s1 = hbg[o] * rsqrtf(hbv[o] + 1e-5f);
    hf[o] = fmaxf((sh + hb[o] - hbm[o]) * s1 + hbb[o], 0.f);
    float s2 = vbg[o] * rsqrtf(vbv[o] + 1e-5f);
    vf[o] = fmaxf((sv + vb_[o] - vbm[o]) * s2 + vbb[o], 0.f);
  }
  for (int o = 0; o < 16; ++o) {
    float sh = fb[o], sv = 0.f;   // fus bias folded into hfc only
#pragma unroll
    for (int c = 0; c < 8; ++c) {
      sh += fw[o * 16 + c] * hf[c];
      sv += fw[o * 16 + 8 + c] * vf[c];
    }
    hfc[(b * 16 + o) * 64 + t] = sh;
    vfc[(b * 16 + o) * 64 + t] = sv;
  }
}

// ---------------- K45 v2: fused gate pipeline + MFMA GEMM ----------------
// 512 thr (8 waves), one (b,h) per block. A[64][528 u16] (pitch 1056B,
// measured conflict-free for the GEMM reads). Column order: cols 0..255 =
// GATED out-ch (global k = 256+c'), cols 256..511 = IDENTITY ch (k = c'-256)
// => B reads use kb^8. Bytes [512,848) of each A row double as
// wsf/bsf/inter during phases 0-2; phase 3 overwrites them with identity.
// LDS = 67.8 KB -> 2 blocks/CU. Direct acc->global epilogue, 4 barriers.
__global__ __launch_bounds__(512, 4) void k45_v2(
    const float* __restrict__ x, const float* __restrict__ r,
    const float* __restrict__ wgct, const float* __restrict__ attn,
    const float* __restrict__ hfc, const float* __restrict__ vfc,
    const float* __restrict__ sfw, const float* __restrict__ sfb,
    const float* __restrict__ sg, const float* __restrict__ sb_,
    const float* __restrict__ sbm, const float* __restrict__ sbv,
    const u16* __restrict__ fwb, const float* __restrict__ fb,
    float* __restrict__ out)
{
  __shared__ __align__(16) u16 A[64 * 528];   // 67584 B
  __shared__ float wgs[16], ats[16], vfhs[16];
  char* Ab = (char*)A;

  int bid = blockIdx.x;
  int b = bid >> 6, h = bid & 63;
  int t = threadIdx.x;

  // ---- P0: broadcast scalars + folded sf weights into overlay ----
  // wsf[o][0..15] f32x4-aligned at row (o&63), bytes 512 + (o>>6)*64
  // bsf[o]        at row (o&63), bytes 768 + (o>>6)*4
  if (t < 16) {
    wgs[t]  = wgct[b * 16 + t];
    ats[t]  = attn[b * 16 + t];
    vfhs[t] = vfc[(b * 16 + t) * 64 + h];
  }
  if (t < 256) {
    int o = t;
    float s = sg[o] * rsqrtf(sbv[o] + 1e-5f);
    float* wrow = (float*)(Ab + (o & 63) * 1056 + 512 + (o >> 6) * 64);
#pragma unroll
    for (int k2 = 0; k2 < 16; ++k2) wrow[k2] = sfw[o * 16 + k2] * s;
    *(float*)(Ab + (o & 63) * 1056 + 768 + (o >> 6) * 4) =
        (sfb[o] - sbm[o]) * s + sb_[o];
  }
  __syncthreads();

  // ---- P1: interaction[k][w] at row w, bytes 784 + k*4 ----
#pragma unroll
  for (int i = 0; i < 2; ++i) {
    int idx = i * 512 + t;
    int k = idx >> 6, w = idx & 63;
    float rv = r[((size_t)(b * 16 + k)) * 4096 + h * 64 + w];
    float rel = sigm(hfc[(b * 16 + k) * 64 + w] + vfhs[k]);
    *(float*)(Ab + w * 1056 + 784 + k * 4) =
        rv * rv * wgs[k] * rel + rv * ats[k];
  }
  __syncthreads();

  // ---- P2: gated half -> A cols [0,256)  (writes bytes [0,512) only) ----
  {
    int w = t & 63, og = t >> 6;
    float iv[16];
#pragma unroll
    for (int k2 = 0; k2 < 16; ++k2)
      iv[k2] = *(const float*)(Ab + w * 1056 + 784 + k2 * 4);
    const float* gsrc = x + ((size_t)(b * 512 + 256)) * 4096 + h * 64 + w;
    for (int j = 0; j < 32; ++j) {
      int o = og * 32 + j;
      const f32x4* wr = (const f32x4*)(Ab + (o & 63) * 1056 + 512 + (o >> 6) * 64);
      f32x4 w0 = wr[0], w1 = wr[1], w2 = wr[2], w3 = wr[3];
      float dot = *(const float*)(Ab + (o & 63) * 1056 + 768 + (o >> 6) * 4);
      dot += iv[0]  * w0[0] + iv[1]  * w0[1] + iv[2]  * w0[2] + iv[3]  * w0[3];
      dot += iv[4]  * w1[0] + iv[5]  * w1[1] + iv[6]  * w1[2] + iv[7]  * w1[3];
      dot += iv[8]  * w2[0] + iv[9]  * w2[1] + iv[10] * w2[2] + iv[11] * w2[3];
      dot += iv[12] * w3[0] + iv[13] * w3[1] + iv[14] * w3[2] + iv[15] * w3[3];
      float gwv = sigm(dot);
      float gv = gsrc[(size_t)o * 4096];
      A[w * 528 + o] = f2bf(gv * gwv);
    }
  }
  __syncthreads();   // wsf/bsf/inter reads complete before overwrite

  // ---- P3: identity transpose -> A cols [256,512) ----
#pragma unroll
  for (int i = 0; i < 8; ++i) {
    int flat = i * 512 + t;
    int c = flat >> 4, q = flat & 15;
    f32x4 v = *(const f32x4*)(x + ((size_t)(b * 512 + c)) * 4096 + h * 64 + q * 4);
#pragma unroll
    for (int j = 0; j < 4; ++j) A[(q * 4 + j) * 528 + 256 + c] = f2bf(v[j]);
  }
  __syncthreads();

  // ---- P4: GEMM (8 waves x 64x64 tiles, B direct from L2) ----
  int lane = t & 63, wv = t >> 6;
  int fr = lane & 15, quad = lane >> 4;
  int n0w = wv * 64;
  f32x4 acc[4][4];
#pragma unroll
  for (int j = 0; j < 4; ++j) {
    float bvv = fb[n0w + j * 16 + fr];
    f32x4 b4 = {bvv, bvv, bvv, bvv};
#pragma unroll
    for (int i = 0; i < 4; ++i) acc[i][j] = b4;
  }
  const u16* Bp = fwb + (size_t)(n0w + fr) * 512 + quad * 8;
  for (int kb = 0; kb < 16; ++kb) {
    int c0 = kb * 32 + quad * 8;
    int kbb = kb ^ 8;                 // A col c' <-> global k = c' ^ 256
    bf16x8 af[4], bfr[4];
#pragma unroll
    for (int i = 0; i < 4; ++i)
      af[i] = *(const bf16x8*)(A + (i * 16 + fr) * 528 + c0);
#pragma unroll
    for (int j = 0; j < 4; ++j)
      bfr[j] = *(const bf16x8*)(Bp + (size_t)(j * 16) * 512 + kbb * 32);
#pragma unroll
    for (int j = 0; j < 4; ++j)
#pragma unroll
      for (int i = 0; i < 4; ++i)
        acc[i][j] = __builtin_amdgcn_mfma_f32_16x16x32_bf16(af[i], bfr[j], acc[i][j], 0, 0, 0);
  }

  // ---- P5: direct epilogue ----
  float* ob = out + ((size_t)(b * 512 + n0w + fr)) * 4096 + h * 64 + quad * 4;
#pragma unroll
  for (int j = 0; j < 4; ++j)
#pragma unroll
    for (int i = 0; i < 4; ++i)
      *(f32x4*)(ob + (size_t)(j * 16) * 4096 + i * 16) = acc[i][j];
}

extern "C" void kernel_launch(void* const* d_in, const int* in_sizes, int n_in,
                              void* d_out, int out_size, void* d_ws, size_t ws_size,
                              hipStream_t stream) {
  const float* x      = (const float*)d_in[0];
  const float* red_w  = (const float*)d_in[1];
  const float* red_b  = (const float*)d_in[2];
  const float* rbg    = (const float*)d_in[3];
  const float* rbb    = (const float*)d_in[4];
  const float* rbm    = (const float*)d_in[5];
  const float* rbv    = (const float*)d_in[6];
  const float* f1w    = (const float*)d_in[7];
  const float* f1b    = (const float*)d_in[8];
  const float* lng    = (const float*)d_in[9];
  const float* lnb    = (const float*)d_in[10];
  const float* f2w    = (const float*)d_in[11];
  const float* f2b    = (const float*)d_in[12];
  const float* rhw    = (const float*)d_in[13];
  const float* rhb    = (const float*)d_in[14];
  const float* rhbg   = (const float*)d_in[15];
  const float* rhbb   = (const float*)d_in[16];
  const float* rhbm   = (const float*)d_in[17];
  const float* rhbv   = (const float*)d_in[18];
  const float* rvw    = (const float*)d_in[19];
  const float* rvb    = (const float*)d_in[20];
  const float* rvbg   = (const float*)d_in[21];
  const float* rvbb   = (const float*)d_in[22];
  const float* rvbm   = (const float*)d_in[23];
  const float* rvbv   = (const float*)d_in[24];
  const float* fusw   = (const float*)d_in[25];
  const float* fusb   = (const float*)d_in[26];
  const float* fcw    = (const float*)d_in[29];
  const float* fcb    = (const float*)d_in[30];
  const float* sfw    = (const float*)d_in[31];
  const float* sfb    = (const float*)d_in[32];
  const float* sbg    = (const float*)d_in[33];
  const float* sbb    = (const float*)d_in[34];
  const float* sbm    = (const float*)d_in[35];
  const float* sbv    = (const float*)d_in[36];
  const float* finw   = (const float*)d_in[37];
  const float* finb   = (const float*)d_in[38];
  float* out = (float*)d_out;

  char* ws = (char*)d_ws;
  size_t off = 0;
  float* r   = (float*)(ws + off); off += (size_t)16 * 16 * 4096 * 4;   // 4 MB
  u16*   fwb = (u16*)(ws + off);   off += (size_t)512 * 512 * 2;        // 512 KB
  float* cm  = (float*)(ws + off); off += 65536;
  float* rm  = (float*)(ws + off); off += 65536;
  float* ctx = (float*)(ws + off); off += 1024;
  float* wg  = (float*)(ws + off); off += 1024;
  float* at  = (float*)(ws + off); off += 1024;
  float* hfc = (float*)(ws + off); off += 65536;
  float* vfc = (float*)(ws + off); off += 65536;

  k0_pack<<<256, 256, 0, stream>>>(finw, fwb);
  k1_reduce<<<256, 256, 0, stream>>>(x, red_w, red_b, rbg, rbb, rbm, rbv, r);
  k2_means<<<256, 256, 0, stream>>>(r, cm, rm, ctx);
  k3a_gct<<<1, 256, 0, stream>>>(ctx, f1w, f1b, lng, lnb, f2w, f2b, fcw, fcb, wg, at);
  k3b_rel<<<16, 64, 0, stream>>>(cm, rm, rhw, rhb, rhbg, rhbb, rhbm, rhbv,
                                 rvw, rvb, rvbg, rvbb, rvbm, rvbv, fusw, fusb, hfc, vfc);
  k45_v2<<<1024, 512, 0, stream>>>(x, r, wg, at, hfc, vfc,
                                   sfw, sfb, sbg, sbb, sbm, sbv, fwb, finb, out);
}

// Round 3
// 423.547 us; speedup vs baseline: 1.2090x; 1.0397x over previous
//
#include <hip/hip_runtime.h>
#include <cstdint>

typedef uint16_t u16;
typedef uint32_t u32;
typedef uint64_t u64;
typedef __attribute__((ext_vector_type(4))) float f32x4;
typedef __attribute__((ext_vector_type(8))) short bf16x8;

__device__ __forceinline__ u16 f2bf(float f) {
  union { float f; u32 i; } u; u.f = f;
  u32 r = u.i + 0x7FFFu + ((u.i >> 16) & 1u);
  return (u16)(r >> 16);
}
__device__ __forceinline__ float sigm(float x) { return 1.f / (1.f + __expf(-x)); }

// ---------------- K1: r = relu(bn(conv1x1(gate))) , fp32 out -------------
__global__ __launch_bounds__(256) void k1_reduce(
    const float* __restrict__ x, const float* __restrict__ rw, const float* __restrict__ rb,
    const float* __restrict__ bg, const float* __restrict__ bb, const float* __restrict__ bm,
    const float* __restrict__ bv, float* __restrict__ r)
{
  __shared__ __align__(16) float wl[256][16];
  __shared__ float bl[16];
  __shared__ float sl[16];
  int t = threadIdx.x;
  if (t < 16) {
    float s = bg[t] * rsqrtf(bv[t] + 1e-5f);
    sl[t] = s;
    bl[t] = (rb[t] - bm[t]) * s + bb[t];
  }
  __syncthreads();
  for (int i = 0; i < 16; ++i) {
    int flat = i * 256 + t;
    int co = flat >> 8, c = flat & 255;
    wl[c][co] = rw[co * 256 + c] * sl[co];
  }
  __syncthreads();
  int p = blockIdx.x * 256 + t;
  int b = p >> 12, pp = p & 4095;
  const float* gsrc = x + ((size_t)(b * 512 + 256)) * 4096 + pp;
  float acc[16];
#pragma unroll
  for (int co = 0; co < 16; ++co) acc[co] = bl[co];
#pragma unroll 8
  for (int c = 0; c < 256; ++c) {
    float g = gsrc[(size_t)c * 4096];
    const f32x4* wr = (const f32x4*)(&wl[c][0]);
    f32x4 a0 = wr[0], a1 = wr[1], a2 = wr[2], a3 = wr[3];
    acc[0]  += g * a0[0]; acc[1]  += g * a0[1]; acc[2]  += g * a0[2]; acc[3]  += g * a0[3];
    acc[4]  += g * a1[0]; acc[5]  += g * a1[1]; acc[6]  += g * a1[2]; acc[7]  += g * a1[3];
    acc[8]  += g * a2[0]; acc[9]  += g * a2[1]; acc[10] += g * a2[2]; acc[11] += g * a2[3];
    acc[12] += g * a3[0]; acc[13] += g * a3[1]; acc[14] += g * a3[2]; acc[15] += g * a3[3];
  }
  float* rd = r + ((size_t)b * 16) * 4096 + pp;
#pragma unroll
  for (int co = 0; co < 16; ++co) rd[(size_t)co * 4096] = fmaxf(acc[co], 0.f);
}

// ---------------- K2: means over h / w / both (LDS-staged) ---------------
__global__ __launch_bounds__(256) void k2_means(
    const float* __restrict__ r, float* __restrict__ cm, float* __restrict__ rm,
    float* __restrict__ ctx)
{
  __shared__ __align__(16) float tile[64][68];
  int bc = blockIdx.x, t = threadIdx.x;
  const float* src = r + (size_t)bc * 4096;
#pragma unroll
  for (int i = 0; i < 4; ++i) {
    int off = (i * 256 + t) * 4;
    int row = off >> 6, col = off & 63;
    f32x4 v = *(const f32x4*)(src + off);
    *(f32x4*)&tile[row][col] = v;
  }
  __syncthreads();
  int wv = t >> 6, lane = t & 63;
  if (wv == 0) {
    float s = 0.f;
    for (int h = 0; h < 64; ++h) s += tile[h][lane];
    cm[bc * 64 + lane] = s * (1.f / 64.f);
    float tot = s;
#pragma unroll
    for (int m = 32; m; m >>= 1) tot += __shfl_xor(tot, m, 64);
    if (lane == 0) ctx[bc] = tot * (1.f / 4096.f);
  } else if (wv == 1) {
    float s = 0.f;
    for (int w0 = 0; w0 < 64; ++w0) s += tile[lane][(w0 + lane) & 63];
    rm[bc * 64 + lane] = s * (1.f / 64.f);
  }
}

// ---------------- K3x: merged k0_pack / k3a_gct / k3b_rel ----------------
// grid 273: [0,256) = fin_w pack, 256 = gct+attn, [257,273) = rel convs
__global__ __launch_bounds__(256) void k3x(
    const float* __restrict__ finw, u16* __restrict__ fwb,
    const float* __restrict__ ctx,
    const float* f1w, const float* f1b, const float* lng, const float* lnb,
    const float* f2w, const float* f2b, const float* fcw, const float* fcb,
    float* __restrict__ wgct, float* __restrict__ attn,
    const float* __restrict__ cm, const float* __restrict__ rm,
    const float* hw, const float* hb, const float* hbg, const float* hbb, const float* hbm, const float* hbv,
    const float* vw, const float* vb_, const float* vbg, const float* vbb, const float* vbm, const float* vbv,
    const float* fw, const float* fb, float* __restrict__ hfc, float* __restrict__ vfc)
{
  int bid = blockIdx.x, t = threadIdx.x;
  if (bid < 256) {
    // ---- k0: pack fin_w -> bf16 ----
    int i = bid * 256 + t;
    f32x4 v = ((const f32x4*)finw)[i];
    u64 p = (u64)f2bf(v[0]) | ((u64)f2bf(v[1]) << 16) |
            ((u64)f2bf(v[2]) << 32) | ((u64)f2bf(v[3]) << 48);
    ((u64*)fwb)[i] = p;
  } else if (bid == 256) {
    // ---- k3a: gct weights + attn ----
    __shared__ float cl[256];
    __shared__ float gl[256];
    cl[t] = ctx[t];
    __syncthreads();
    int b = t >> 4, c = t & 15;
    const float* cb = &cl[b * 16];
    float a[4];
#pragma unroll
    for (int j = 0; j < 4; ++j) {
      float s = f1b[j];
      for (int i = 0; i < 16; ++i) s += cb[i] * f1w[j * 16 + i];
      a[j] = s;
    }
    float mu = 0.25f * (a[0] + a[1] + a[2] + a[3]);
    float var = 0.f;
#pragma unroll
    for (int j = 0; j < 4; ++j) { float d = a[j] - mu; var += d * d; }
    var *= 0.25f;
    float inv = rsqrtf(var + 1e-5f);
#pragma unroll
    for (int j = 0; j < 4; ++j)
      a[j] = fmaxf((a[j] - mu) * inv * lng[j] + lnb[j], 0.f);
    float s2 = f2b[c];
#pragma unroll
    for (int j = 0; j < 4; ++j) s2 += a[j] * f2w[c * 4 + j];
    wgct[t] = sigm(s2);
    float g = fcb[c];
    for (int i = 0; i < 16; ++i) g += cb[i] * fcw[c * 16 + i];
    gl[t] = g;
    __syncthreads();
    const float* gb = &gl[b * 16];
    float mx = -1e30f;
    for (int i = 0; i < 16; ++i) mx = fmaxf(mx, gb[i]);
    float den = 0.f;
    for (int i = 0; i < 16; ++i) den += __expf(gb[i] - mx);
    attn[t] = __expf(g - mx) / den;
  } else {
    // ---- k3b: rel h/v 1D convs ----
    __shared__ float cml[16][64], rml[16][64];
    int b = bid - 257;
#pragma unroll
    for (int i = 0; i < 4; ++i) {
      int idx = i * 256 + t;
      int row = idx >> 6, col = idx & 63;
      cml[row][col] = cm[(b * 16 + row) * 64 + col];
      rml[row][col] = rm[(b * 16 + row) * 64 + col];
    }
    __syncthreads();
    if (t < 64) {
      float hf[8], vf[8];
      for (int o = 0; o < 8; ++o) {
        float sh = 0.f, sv = 0.f;
        for (int ci = 0; ci < 16; ++ci) {
#pragma unroll
          for (int kk = 0; kk < 3; ++kk) {
            int q = t + kk - 1;
            bool ok = (q >= 0 && q < 64);
            int qi = ok ? q : 0;
            float xh = ok ? cml[ci][qi] : 0.f;
            float xv = ok ? rml[ci][qi] : 0.f;
            sh += hw[(o * 16 + ci) * 3 + kk] * xh;
            sv += vw[(o * 16 + ci) * 3 + kk] * xv;
          }
        }
        float s1 = hbg[o] * rsqrtf(hbv[o] + 1e-5f);
        hf[o] = fmaxf((sh + hb[o] - hbm[o]) * s1 + hbb[o], 0.f);
        float s2 = vbg[o] * rsqrtf(vbv[o] + 1e-5f);
        vf[o] = fmaxf((sv + vb_[o] - vbm[o]) * s2 + vbb[o], 0.f);
      }
      for (int o = 0; o < 16; ++o) {
        float sh = fb[o], sv = 0.f;   // fus bias folded into hfc only
#pragma unroll
        for (int c = 0; c < 8; ++c) {
          sh += fw[o * 16 + c] * hf[c];
          sv += fw[o * 16 + 8 + c] * vf[c];
        }
        hfc[(b * 16 + o) * 64 + t] = sh;
        vfc[(b * 16 + o) * 64 + t] = sv;
      }
    }
  }
}

// ---------------- K45 v3: fused gate pipeline + MFMA GEMM ----------------
// 512 thr (8 waves), one (b,h) per block. A[64][520 u16] pitch 1040 B
// (260 dw; 260/4 = 65 odd -> row-indexed 16B accesses spread over all 8
// bank-groups). Cols [0,256) = gated (k=256+c'), [256,512) = identity
// (k=c'-256) => B k-offset uses kb^8. Overlay (dead before P3):
//   wsf[o][16] f32 @ row (o&63), byte 512+(o>>6)*64
//   bsf[o]         @ row (o&63), byte 768+(o>>6)*4
//   inter[k][w]    @ row w,      byte 784+k*4
// P2 writes b128 bundles (conflict-free); P3 transposes in-register via
// ds_bpermute + b64 row-writes (no scatter u16, no extra barriers).
// 3 barriers total. LDS = 66560 B -> 2 blocks/CU.
__global__ __launch_bounds__(512, 4) void k45_v3(
    const float* __restrict__ x, const float* __restrict__ r,
    const float* __restrict__ wgct, const float* __restrict__ attn,
    const float* __restrict__ hfc, const float* __restrict__ vfc,
    const float* __restrict__ sfw, const float* __restrict__ sfb,
    const float* __restrict__ sg, const float* __restrict__ sb_,
    const float* __restrict__ sbm, const float* __restrict__ sbv,
    const u16* __restrict__ fwb, const float* __restrict__ fb,
    float* __restrict__ out)
{
  __shared__ __align__(16) u16 A[64 * 520];   // 66560 B
  char* Ab = (char*)A;

  int bid = blockIdx.x;
  int b = bid >> 6, h = bid & 63;
  int t = threadIdx.x;
  int lane = t & 63, wv = t >> 6;

  // ---- P0 (waves 0-3): folded sf weights + bias into overlay ----
  if (t < 256) {
    int o = t;
    float s = sg[o] * rsqrtf(sbv[o] + 1e-5f);
    const f32x4* sw = (const f32x4*)(sfw + o * 16);
    f32x4 w0 = sw[0] * s, w1 = sw[1] * s, w2 = sw[2] * s, w3 = sw[3] * s;
    f32x4* wrow = (f32x4*)(Ab + (o & 63) * 1040 + 512 + (o >> 6) * 64);
    wrow[0] = w0; wrow[1] = w1; wrow[2] = w2; wrow[3] = w3;
    *(float*)(Ab + (o & 63) * 1040 + 768 + (o >> 6) * 4) =
        (sfb[o] - sbm[o]) * s + sb_[o];
  }
  // ---- P1 (all waves, no dependency on P0): interaction[k][w] ----
#pragma unroll
  for (int i = 0; i < 2; ++i) {
    int idx = i * 512 + t;
    int k = idx >> 6, w = idx & 63;
    float rv = r[((size_t)(b * 16 + k)) * 4096 + h * 64 + w];
    float rel = sigm(hfc[(b * 16 + k) * 64 + w] + vfc[(b * 16 + k) * 64 + h]);
    *(float*)(Ab + w * 1040 + 784 + k * 4) =
        rv * rv * wgct[b * 16 + k] * rel + rv * attn[b * 16 + k];
  }
  __syncthreads();

  // ---- P2: gated half -> A cols [0,256), b128 bundled writes ----
  {
    int w = t & 63, og = t >> 6;
    const char* irow = Ab + w * 1040 + 784;
    f32x4 iv0 = *(const f32x4*)(irow);
    f32x4 iv1 = *(const f32x4*)(irow + 16);
    f32x4 iv2 = *(const f32x4*)(irow + 32);
    f32x4 iv3 = *(const f32x4*)(irow + 48);
    const float* gsrc = x + ((size_t)(b * 512 + 256)) * 4096 + h * 64 + w;
#pragma unroll
    for (int jo = 0; jo < 4; ++jo) {
      bf16x8 vb;
#pragma unroll
      for (int jj = 0; jj < 8; ++jj) {
        int o = og * 32 + jo * 8 + jj;
        const char* orow = Ab + (o & 63) * 1040;
        const f32x4* wr = (const f32x4*)(orow + 512 + (o >> 6) * 64);
        f32x4 w0 = wr[0], w1 = wr[1], w2 = wr[2], w3 = wr[3];
        float dot = *(const float*)(orow + 768 + (o >> 6) * 4);
        dot += iv0[0] * w0[0] + iv0[1] * w0[1] + iv0[2] * w0[2] + iv0[3] * w0[3];
        dot += iv1[0] * w1[0] + iv1[1] * w1[1] + iv1[2] * w1[2] + iv1[3] * w1[3];
        dot += iv2[0] * w2[0] + iv2[1] * w2[1] + iv2[2] * w2[2] + iv2[3] * w2[3];
        dot += iv3[0] * w3[0] + iv3[1] * w3[1] + iv3[2] * w3[2] + iv3[3] * w3[3];
        float gwv = sigm(dot);
        float gv = gsrc[(size_t)o * 4096];
        vb[jj] = (short)f2bf(gv * gwv);
      }
      *(bf16x8*)(Ab + w * 1040 + (og * 32 + jo * 8) * 2) = vb;
    }
  }
  __syncthreads();   // overlay reads done before P3 overwrites [512,1024)

  // ---- P3: identity -> A cols [256,512) via in-register transpose ----
  // source role: lane holds (q = lane&15, c = base + (lane>>4)), 4 pixels
  // dest role:   lane writes row m = 4*(lane&15) + (lane>>4), 4 cols (b64)
  {
    int q = lane & 15, cg = lane >> 4;
    int qp = lane & 15, jp = lane >> 4;
    int m = qp * 4 + jp;
#pragma unroll
    for (int i = 0; i < 8; ++i) {
      int c = i * 32 + wv * 4 + cg;
      f32x4 v = *(const f32x4*)(x + ((size_t)(b * 512 + c)) * 4096 + h * 64 + q * 4);
      u32 w01 = (u32)f2bf(v[0]) | ((u32)f2bf(v[1]) << 16);
      u32 w23 = (u32)f2bf(v[2]) | ((u32)f2bf(v[3]) << 16);
      u32 e[4];
#pragma unroll
      for (int cp = 0; cp < 4; ++cp) {
        int srcaddr = (cp * 16 + qp) << 2;
        u32 r01 = (u32)__builtin_amdgcn_ds_bpermute(srcaddr, (int)w01);
        u32 r23 = (u32)__builtin_amdgcn_ds_bpermute(srcaddr, (int)w23);
        u32 sel = (jp < 2) ? r01 : r23;
        e[cp] = (jp & 1) ? (sel >> 16) : (sel & 0xffffu);
      }
      u64 pk = (u64)e[0] | ((u64)e[1] << 16) | ((u64)e[2] << 32) | ((u64)e[3] << 48);
      *(u64*)(Ab + m * 1040 + 512 + (i * 32 + wv * 4) * 2) = pk;
    }
  }
  __syncthreads();

  // ---- P4: GEMM (8 waves x 64x64 tiles, B direct from L2) ----
  int fr = lane & 15, quad = lane >> 4;
  int n0w = wv * 64;
  f32x4 acc[4][4];
#pragma unroll
  for (int j = 0; j < 4; ++j) {
    float bvv = fb[n0w + j * 16 + fr];
    f32x4 b4 = {bvv, bvv, bvv, bvv};
#pragma unroll
    for (int i = 0; i < 4; ++i) acc[i][j] = b4;
  }
  const u16* Bp = fwb + (size_t)(n0w + fr) * 512 + quad * 8;
  for (int kb = 0; kb < 16; ++kb) {
    int c0 = kb * 32 + quad * 8;
    int kbb = kb ^ 8;                 // A col c' <-> global k = c' ^ 256
    bf16x8 af[4], bfr[4];
#pragma unroll
    for (int i = 0; i < 4; ++i)
      af[i] = *(const bf16x8*)(A + (i * 16 + fr) * 520 + c0);
#pragma unroll
    for (int j = 0; j < 4; ++j)
      bfr[j] = *(const bf16x8*)(Bp + (size_t)(j * 16) * 512 + kbb * 32);
#pragma unroll
    for (int j = 0; j < 4; ++j)
#pragma unroll
      for (int i = 0; i < 4; ++i)
        acc[i][j] = __builtin_amdgcn_mfma_f32_16x16x32_bf16(af[i], bfr[j], acc[i][j], 0, 0, 0);
  }

  // ---- P5: direct epilogue ----
  float* ob = out + ((size_t)(b * 512 + n0w + fr)) * 4096 + h * 64 + quad * 4;
#pragma unroll
  for (int j = 0; j < 4; ++j)
#pragma unroll
    for (int i = 0; i < 4; ++i)
      *(f32x4*)(ob + (size_t)(j * 16) * 4096 + i * 16) = acc[i][j];
}

extern "C" void kernel_launch(void* const* d_in, const int* in_sizes, int n_in,
                              void* d_out, int out_size, void* d_ws, size_t ws_size,
                              hipStream_t stream) {
  const float* x      = (const float*)d_in[0];
  const float* red_w  = (const float*)d_in[1];
  const float* red_b  = (const float*)d_in[2];
  const float* rbg    = (const float*)d_in[3];
  const float* rbb    = (const float*)d_in[4];
  const float* rbm    = (const float*)d_in[5];
  const float* rbv    = (const float*)d_in[6];
  const float* f1w    = (const float*)d_in[7];
  const float* f1b    = (const float*)d_in[8];
  const float* lng    = (const float*)d_in[9];
  const float* lnb    = (const float*)d_in[10];
  const float* f2w    = (const float*)d_in[11];
  const float* f2b    = (const float*)d_in[12];
  const float* rhw    = (const float*)d_in[13];
  const float* rhb    = (const float*)d_in[14];
  const float* rhbg   = (const float*)d_in[15];
  const float* rhbb   = (const float*)d_in[16];
  const float* rhbm   = (const float*)d_in[17];
  const float* rhbv   = (const float*)d_in[18];
  const float* rvw    = (const float*)d_in[19];
  const float* rvb    = (const float*)d_in[20];
  const float* rvbg   = (const float*)d_in[21];
  const float* rvbb   = (const float*)d_in[22];
  const float* rvbm   = (const float*)d_in[23];
  const float* rvbv   = (const float*)d_in[24];
  const float* fusw   = (const float*)d_in[25];
  const float* fusb   = (const float*)d_in[26];
  const float* fcw    = (const float*)d_in[29];
  const float* fcb    = (const float*)d_in[30];
  const float* sfw    = (const float*)d_in[31];
  const float* sfb    = (const float*)d_in[32];
  const float* sbg    = (const float*)d_in[33];
  const float* sbb    = (const float*)d_in[34];
  const float* sbm    = (const float*)d_in[35];
  const float* sbv    = (const float*)d_in[36];
  const float* finw   = (const float*)d_in[37];
  const float* finb   = (const float*)d_in[38];
  float* out = (float*)d_out;

  char* ws = (char*)d_ws;
  size_t off = 0;
  float* r   = (float*)(ws + off); off += (size_t)16 * 16 * 4096 * 4;   // 4 MB
  u16*   fwb = (u16*)(ws + off);   off += (size_t)512 * 512 * 2;        // 512 KB
  float* cm  = (float*)(ws + off); off += 65536;
  float* rm  = (float*)(ws + off); off += 65536;
  float* ctx = (float*)(ws + off); off += 1024;
  float* wg  = (float*)(ws + off); off += 1024;
  float* at  = (float*)(ws + off); off += 1024;
  float* hfc = (float*)(ws + off); off += 65536;
  float* vfc = (float*)(ws + off); off += 65536;

  k1_reduce<<<256, 256, 0, stream>>>(x, red_w, red_b, rbg, rbb, rbm, rbv, r);
  k2_means<<<256, 256, 0, stream>>>(r, cm, rm, ctx);
  k3x<<<273, 256, 0, stream>>>(finw, fwb,
                               ctx, f1w, f1b, lng, lnb, f2w, f2b, fcw, fcb, wg, at,
                               cm, rm, rhw, rhb, rhbg, rhbb, rhbm, rhbv,
                               rvw, rvb, rvbg, rvbb, rvbm, rvbv, fusw, fusb, hfc, vfc);
  k45_v3<<<1024, 512, 0, stream>>>(x, r, wg, at, hfc, vfc,
                                   sfw, sfb, sbg, sbb, sbm, sbv, fwb, finb, out);
}

// Round 4
// 401.141 us; speedup vs baseline: 1.2765x; 1.0559x over previous
//
#include <hip/hip_runtime.h>
#include <cstdint>

typedef uint16_t u16;
typedef uint32_t u32;
typedef uint64_t u64;
typedef __attribute__((ext_vector_type(4))) float f32x4;
typedef __attribute__((ext_vector_type(8))) short bf16x8;

__device__ __forceinline__ u16 f2bf(float f) {
  union { float f; u32 i; } u; u.f = f;
  u32 r = u.i + 0x7FFFu + ((u.i >> 16) & 1u);
  return (u16)(r >> 16);
}
__device__ __forceinline__ float sigm(float x) { return 1.f / (1.f + __expf(-x)); }

// ---------------- K1 v2: r = relu(bn(conv1x1(gate))) ---------------------
// 1024 blocks x 256 thr; block = 64 pixels, 4 channel-groups of 64.
// 4 blocks/CU (35 KB LDS), 4 waves/SIMD -> 4x in-flight loads vs v1.
__global__ __launch_bounds__(256, 4) void k1_reduce(
    const float* __restrict__ x, const float* __restrict__ rw, const float* __restrict__ rb,
    const float* __restrict__ bg, const float* __restrict__ bb, const float* __restrict__ bm,
    const float* __restrict__ bv, float* __restrict__ r)
{
  __shared__ __align__(16) float wl[256][16];
  __shared__ float bl[16];
  __shared__ float sl[16];
  __shared__ float sc[4][64][17];
  int t = threadIdx.x;
  if (t < 16) {
    float s = bg[t] * rsqrtf(bv[t] + 1e-5f);
    sl[t] = s;
    bl[t] = (rb[t] - bm[t]) * s + bb[t];
  }
  __syncthreads();
  for (int i = 0; i < 16; ++i) {
    int flat = i * 256 + t;
    int co = flat >> 8, c = flat & 255;
    wl[c][co] = rw[co * 256 + c] * sl[co];
  }
  __syncthreads();
  int g = t >> 6, l = t & 63;
  int pg = blockIdx.x * 64 + l;
  int b = pg >> 12, pp = pg & 4095;
  const float* gsrc = x + ((size_t)(b * 512 + 256 + g * 64)) * 4096 + pp;
  float acc[16];
#pragma unroll
  for (int co = 0; co < 16; ++co) acc[co] = 0.f;
#pragma unroll 8
  for (int c = 0; c < 64; ++c) {
    float gv = gsrc[(size_t)c * 4096];
    const f32x4* wr = (const f32x4*)(&wl[g * 64 + c][0]);
    f32x4 a0 = wr[0], a1 = wr[1], a2 = wr[2], a3 = wr[3];
    acc[0]  += gv * a0[0]; acc[1]  += gv * a0[1]; acc[2]  += gv * a0[2]; acc[3]  += gv * a0[3];
    acc[4]  += gv * a1[0]; acc[5]  += gv * a1[1]; acc[6]  += gv * a1[2]; acc[7]  += gv * a1[3];
    acc[8]  += gv * a2[0]; acc[9]  += gv * a2[1]; acc[10] += gv * a2[2]; acc[11] += gv * a2[3];
    acc[12] += gv * a3[0]; acc[13] += gv * a3[1]; acc[14] += gv * a3[2]; acc[15] += gv * a3[3];
  }
#pragma unroll
  for (int co = 0; co < 16; ++co) sc[g][l][co] = acc[co];
  __syncthreads();
  int ppb = (blockIdx.x * 64) & 4095;
#pragma unroll
  for (int i = 0; i < 4; ++i) {
    int idx = i * 256 + t;
    int l2 = idx & 63, co = idx >> 6;
    float s = sc[0][l2][co] + sc[1][l2][co] + sc[2][l2][co] + sc[3][l2][co] + bl[co];
    r[((size_t)(b * 16 + co)) * 4096 + ppb + l2] = fmaxf(s, 0.f);
  }
}

// ---------------- K2: means over h / w / both (LDS-staged) ---------------
__global__ __launch_bounds__(256) void k2_means(
    const float* __restrict__ r, float* __restrict__ cm, float* __restrict__ rm,
    float* __restrict__ ctx)
{
  __shared__ __align__(16) float tile[64][68];
  int bc = blockIdx.x, t = threadIdx.x;
  const float* src = r + (size_t)bc * 4096;
#pragma unroll
  for (int i = 0; i < 4; ++i) {
    int off = (i * 256 + t) * 4;
    int row = off >> 6, col = off & 63;
    f32x4 v = *(const f32x4*)(src + off);
    *(f32x4*)&tile[row][col] = v;
  }
  __syncthreads();
  int wv = t >> 6, lane = t & 63;
  if (wv == 0) {
    float s = 0.f;
    for (int h = 0; h < 64; ++h) s += tile[h][lane];
    cm[bc * 64 + lane] = s * (1.f / 64.f);
    float tot = s;
#pragma unroll
    for (int m = 32; m; m >>= 1) tot += __shfl_xor(tot, m, 64);
    if (lane == 0) ctx[bc] = tot * (1.f / 4096.f);
  } else if (wv == 1) {
    float s = 0.f;
    for (int w0 = 0; w0 < 64; ++w0) s += tile[lane][(w0 + lane) & 63];
    rm[bc * 64 + lane] = s * (1.f / 64.f);
  }
}

// ---------------- K3x: merged k0_pack / k3a_gct / k3b_rel ----------------
// grid 273: [0,256) = fin_w pack, 256 = gct+attn, [257,273) = rel convs
__global__ __launch_bounds__(256) void k3x(
    const float* __restrict__ finw, u16* __restrict__ fwb,
    const float* __restrict__ ctx,
    const float* f1w, const float* f1b, const float* lng, const float* lnb,
    const float* f2w, const float* f2b, const float* fcw, const float* fcb,
    float* __restrict__ wgct, float* __restrict__ attn,
    const float* __restrict__ cm, const float* __restrict__ rm,
    const float* hw, const float* hb, const float* hbg, const float* hbb, const float* hbm, const float* hbv,
    const float* vw, const float* vb_, const float* vbg, const float* vbb, const float* vbm, const float* vbv,
    const float* fw, const float* fb, float* __restrict__ hfc, float* __restrict__ vfc)
{
  int bid = blockIdx.x, t = threadIdx.x;
  if (bid < 256) {
    int i = bid * 256 + t;
    f32x4 v = ((const f32x4*)finw)[i];
    u64 p = (u64)f2bf(v[0]) | ((u64)f2bf(v[1]) << 16) |
            ((u64)f2bf(v[2]) << 32) | ((u64)f2bf(v[3]) << 48);
    ((u64*)fwb)[i] = p;
  } else if (bid == 256) {
    __shared__ float cl[256];
    __shared__ float gl[256];
    cl[t] = ctx[t];
    __syncthreads();
    int b = t >> 4, c = t & 15;
    const float* cb = &cl[b * 16];
    float a[4];
#pragma unroll
    for (int j = 0; j < 4; ++j) {
      float s = f1b[j];
      for (int i = 0; i < 16; ++i) s += cb[i] * f1w[j * 16 + i];
      a[j] = s;
    }
    float mu = 0.25f * (a[0] + a[1] + a[2] + a[3]);
    float var = 0.f;
#pragma unroll
    for (int j = 0; j < 4; ++j) { float d = a[j] - mu; var += d * d; }
    var *= 0.25f;
    float inv = rsqrtf(var + 1e-5f);
#pragma unroll
    for (int j = 0; j < 4; ++j)
      a[j] = fmaxf((a[j] - mu) * inv * lng[j] + lnb[j], 0.f);
    float s2 = f2b[c];
#pragma unroll
    for (int j = 0; j < 4; ++j) s2 += a[j] * f2w[c * 4 + j];
    wgct[t] = sigm(s2);
    float g = fcb[c];
    for (int i = 0; i < 16; ++i) g += cb[i] * fcw[c * 16 + i];
    gl[t] = g;
    __syncthreads();
    const float* gb = &gl[b * 16];
    float mx = -1e30f;
    for (int i = 0; i < 16; ++i) mx = fmaxf(mx, gb[i]);
    float den = 0.f;
    for (int i = 0; i < 16; ++i) den += __expf(gb[i] - mx);
    attn[t] = __expf(g - mx) / den;
  } else {
    __shared__ float cml[16][64], rml[16][64];
    int b = bid - 257;
#pragma unroll
    for (int i = 0; i < 4; ++i) {
      int idx = i * 256 + t;
      int row = idx >> 6, col = idx & 63;
      cml[row][col] = cm[(b * 16 + row) * 64 + col];
      rml[row][col] = rm[(b * 16 + row) * 64 + col];
    }
    __syncthreads();
    if (t < 64) {
      float hf[8], vf[8];
      for (int o = 0; o < 8; ++o) {
        float sh = 0.f, sv = 0.f;
        for (int ci = 0; ci < 16; ++ci) {
#pragma unroll
          for (int kk = 0; kk < 3; ++kk) {
            int q = t + kk - 1;
            bool ok = (q >= 0 && q < 64);
            int qi = ok ? q : 0;
            float xh = ok ? cml[ci][qi] : 0.f;
            float xv = ok ? rml[ci][qi] : 0.f;
            sh += hw[(o * 16 + ci) * 3 + kk] * xh;
            sv += vw[(o * 16 + ci) * 3 + kk] * xv;
          }
        }
        float s1 = hbg[o] * rsqrtf(hbv[o] + 1e-5f);
        hf[o] = fmaxf((sh + hb[o] - hbm[o]) * s1 + hbb[o], 0.f);
        float s2 = vbg[o] * rsqrtf(vbv[o] + 1e-5f);
        vf[o] = fmaxf((sv + vb_[o] - vbm[o]) * s2 + vbb[o], 0.f);
      }
      for (int o = 0; o < 16; ++o) {
        float sh = fb[o], sv = 0.f;   // fus bias folded into hfc only
#pragma unroll
        for (int c = 0; c < 8; ++c) {
          sh += fw[o * 16 + c] * hf[c];
          sv += fw[o * 16 + 8 + c] * vf[c];
        }
        hfc[(b * 16 + o) * 64 + t] = sh;
        vfc[(b * 16 + o) * 64 + t] = sv;
      }
    }
  }
}

// ---------------- K45 v4: fused gate pipeline + MFMA GEMM ----------------
// Pitch back to 528 u16 (1056 B, R1-measured conflict-free base) + uniform
// XOR swizzle: every column byte cb of row m is stored at cb ^ ((m&7)<<4).
// Applied to overlay (wsf/bsf/inter), P2/P3 staging writes, GEMM af reads.
// P3 merges column pairs -> one ds_write_b128 per lane (slot-balanced).
// Cols [0,256) gated (k=256+c'), [256,512) identity -> B uses kb^8.
// 3 barriers. LDS 67584 B -> 2 blocks/CU.
__global__ __launch_bounds__(512, 4) void k45_v4(
    const float* __restrict__ x, const float* __restrict__ r,
    const float* __restrict__ wgct, const float* __restrict__ attn,
    const float* __restrict__ hfc, const float* __restrict__ vfc,
    const float* __restrict__ sfw, const float* __restrict__ sfb,
    const float* __restrict__ sg, const float* __restrict__ sb_,
    const float* __restrict__ sbm, const float* __restrict__ sbv,
    const u16* __restrict__ fwb, const float* __restrict__ fb,
    float* __restrict__ out)
{
  __shared__ __align__(16) u16 A[64 * 528];   // 67584 B
  char* Ab = (char*)A;

  int bid = blockIdx.x;
  int b = bid >> 6, h = bid & 63;
  int t = threadIdx.x;
  int lane = t & 63, wv = t >> 6;

  // ---- P0: folded sf weights + bias into overlay (swizzled) ----
  if (t < 256) {
    int o = t;
    int orow = o & 63, ov = (orow & 7) << 4, ohi = o >> 6;
    float s = sg[o] * rsqrtf(sbv[o] + 1e-5f);
    const f32x4* sw = (const f32x4*)(sfw + o * 16);
    char* rbase = Ab + orow * 1056;
#pragma unroll
    for (int j = 0; j < 4; ++j)
      *(f32x4*)(rbase + ((512 + ohi * 64 + j * 16) ^ ov)) = sw[j] * s;
    *(float*)(rbase + ((768 + ohi * 4) ^ ov)) =
        (sfb[o] - sbm[o]) * s + sb_[o];
  }
  // ---- P1: interaction[k][w] into overlay (swizzled) ----
#pragma unroll
  for (int i = 0; i < 2; ++i) {
    int idx = i * 512 + t;
    int k = idx >> 6, w = idx & 63;
    float rv = r[((size_t)(b * 16 + k)) * 4096 + h * 64 + w];
    float rel = sigm(hfc[(b * 16 + k) * 64 + w] + vfc[(b * 16 + k) * 64 + h]);
    *(float*)(Ab + w * 1056 + ((784 + k * 4) ^ ((w & 7) << 4))) =
        rv * rv * wgct[b * 16 + k] * rel + rv * attn[b * 16 + k];
  }
  __syncthreads();

  // ---- P2: gated half -> A cols [0,256), b128 swizzled writes ----
  {
    int w = t & 63, og = t >> 6;
    int wx = (w & 7) << 4;
    const char* irow = Ab + w * 1056;
    f32x4 iv0 = *(const f32x4*)(irow + ((784 +  0) ^ wx));
    f32x4 iv1 = *(const f32x4*)(irow + ((784 + 16) ^ wx));
    f32x4 iv2 = *(const f32x4*)(irow + ((784 + 32) ^ wx));
    f32x4 iv3 = *(const f32x4*)(irow + ((784 + 48) ^ wx));
    const float* gsrc = x + ((size_t)(b * 512 + 256)) * 4096 + h * 64 + w;
#pragma unroll
    for (int jo = 0; jo < 4; ++jo) {
      bf16x8 vb;
#pragma unroll
      for (int jj = 0; jj < 8; ++jj) {
        int o = og * 32 + jo * 8 + jj;
        int orow = o & 63, ov = (orow & 7) << 4, ohi = o >> 6;
        const char* rbase = Ab + orow * 1056;
        f32x4 w0 = *(const f32x4*)(rbase + ((512 + ohi * 64 +  0) ^ ov));
        f32x4 w1 = *(const f32x4*)(rbase + ((512 + ohi * 64 + 16) ^ ov));
        f32x4 w2 = *(const f32x4*)(rbase + ((512 + ohi * 64 + 32) ^ ov));
        f32x4 w3 = *(const f32x4*)(rbase + ((512 + ohi * 64 + 48) ^ ov));
        float dot = *(const float*)(rbase + ((768 + ohi * 4) ^ ov));
        dot += iv0[0] * w0[0] + iv0[1] * w0[1] + iv0[2] * w0[2] + iv0[3] * w0[3];
        dot += iv1[0] * w1[0] + iv1[1] * w1[1] + iv1[2] * w1[2] + iv1[3] * w1[3];
        dot += iv2[0] * w2[0] + iv2[1] * w2[1] + iv2[2] * w2[2] + iv2[3] * w2[3];
        dot += iv3[0] * w3[0] + iv3[1] * w3[1] + iv3[2] * w3[2] + iv3[3] * w3[3];
        float gwv = sigm(dot);
        float gv = gsrc[(size_t)o * 4096];
        vb[jj] = (short)f2bf(gv * gwv);
      }
      *(bf16x8*)(Ab + w * 1056 + ((og * 64 + jo * 16) ^ wx)) = vb;
    }
  }
  __syncthreads();   // overlay reads done before P3 overwrites [512,1024)

  // ---- P3: identity -> A cols [256,512), bpermute transpose + b128 ----
  // Per pair-iter: lane loads 2 f32x4 (cols cA=base+cg, cB=cA+4), gathers
  // 8 contiguous cols for its row m = 4*(lane&15)+(lane>>4), one b128.
  {
    int q = lane & 15, cg = lane >> 4;
    int m = q * 4 + cg;                 // dest row (qp=q, jp=cg)
    int mx = (m & 7) << 4;
#pragma unroll
    for (int i = 0; i < 4; ++i) {
      int cbase = i * 64 + wv * 8;
      f32x4 vA = *(const f32x4*)(x + ((size_t)(b * 512 + cbase + cg)) * 4096 + h * 64 + q * 4);
      f32x4 vB = *(const f32x4*)(x + ((size_t)(b * 512 + cbase + 4 + cg)) * 4096 + h * 64 + q * 4);
      u32 a01 = (u32)f2bf(vA[0]) | ((u32)f2bf(vA[1]) << 16);
      u32 a23 = (u32)f2bf(vA[2]) | ((u32)f2bf(vA[3]) << 16);
      u32 b01 = (u32)f2bf(vB[0]) | ((u32)f2bf(vB[1]) << 16);
      u32 b23 = (u32)f2bf(vB[2]) | ((u32)f2bf(vB[3]) << 16);
      int jp = cg;
      u32 e[8];
#pragma unroll
      for (int cp = 0; cp < 4; ++cp) {
        int srcaddr = (cp * 16 + q) << 2;
        u32 rA01 = (u32)__builtin_amdgcn_ds_bpermute(srcaddr, (int)a01);
        u32 rA23 = (u32)__builtin_amdgcn_ds_bpermute(srcaddr, (int)a23);
        u32 rB01 = (u32)__builtin_amdgcn_ds_bpermute(srcaddr, (int)b01);
        u32 rB23 = (u32)__builtin_amdgcn_ds_bpermute(srcaddr, (int)b23);
        u32 selA = (jp < 2) ? rA01 : rA23;
        u32 selB = (jp < 2) ? rB01 : rB23;
        e[cp]     = (jp & 1) ? (selA >> 16) : (selA & 0xffffu);
        e[4 + cp] = (jp & 1) ? (selB >> 16) : (selB & 0xffffu);
      }
      bf16x8 pk;
#pragma unroll
      for (int j = 0; j < 8; ++j) pk[j] = (short)e[j];
      *(bf16x8*)(Ab + m * 1056 + ((512 + i * 128 + wv * 16) ^ mx)) = pk;
    }
  }
  __syncthreads();

  // ---- P4: GEMM (8 waves x 64x64 tiles, B direct from L2) ----
  int fr = lane & 15, quad = lane >> 4;
  int fx = (fr & 7) << 4;
  int n0w = wv * 64;
  f32x4 acc[4][4];
#pragma unroll
  for (int j = 0; j < 4; ++j) {
    float bvv = fb[n0w + j * 16 + fr];
    f32x4 b4 = {bvv, bvv, bvv, bvv};
#pragma unroll
    for (int i = 0; i < 4; ++i) acc[i][j] = b4;
  }
  const u16* Bp = fwb + (size_t)(n0w + fr) * 512 + quad * 8;
  for (int kb = 0; kb < 16; ++kb) {
    int kbb = kb ^ 8;                 // A col c' <-> global k = c' ^ 256
    bf16x8 af[4], bfr[4];
#pragma unroll
    for (int i = 0; i < 4; ++i)
      af[i] = *(const bf16x8*)(Ab + (size_t)(i * 16 + fr) * 1056 +
                               ((kb * 64 + quad * 16) ^ fx));
#pragma unroll
    for (int j = 0; j < 4; ++j)
      bfr[j] = *(const bf16x8*)(Bp + (size_t)(j * 16) * 512 + kbb * 32);
#pragma unroll
    for (int j = 0; j < 4; ++j)
#pragma unroll
      for (int i = 0; i < 4; ++i)
        acc[i][j] = __builtin_amdgcn_mfma_f32_16x16x32_bf16(af[i], bfr[j], acc[i][j], 0, 0, 0);
  }

  // ---- P5: direct epilogue ----
  float* ob = out + ((size_t)(b * 512 + n0w + fr)) * 4096 + h * 64 + quad * 4;
#pragma unroll
  for (int j = 0; j < 4; ++j)
#pragma unroll
    for (int i = 0; i < 4; ++i)
      *(f32x4*)(ob + (size_t)(j * 16) * 4096 + i * 16) = acc[i][j];
}

extern "C" void kernel_launch(void* const* d_in, const int* in_sizes, int n_in,
                              void* d_out, int out_size, void* d_ws, size_t ws_size,
                              hipStream_t stream) {
  const float* x      = (const float*)d_in[0];
  const float* red_w  = (const float*)d_in[1];
  const float* red_b  = (const float*)d_in[2];
  const float* rbg    = (const float*)d_in[3];
  const float* rbb    = (const float*)d_in[4];
  const float* rbm    = (const float*)d_in[5];
  const float* rbv    = (const float*)d_in[6];
  const float* f1w    = (const float*)d_in[7];
  const float* f1b    = (const float*)d_in[8];
  const float* lng    = (const float*)d_in[9];
  const float* lnb    = (const float*)d_in[10];
  const float* f2w    = (const float*)d_in[11];
  const float* f2b    = (const float*)d_in[12];
  const float* rhw    = (const float*)d_in[13];
  const float* rhb    = (const float*)d_in[14];
  const float* rhbg   = (const float*)d_in[15];
  const float* rhbb   = (const float*)d_in[16];
  const float* rhbm   = (const float*)d_in[17];
  const float* rhbv   = (const float*)d_in[18];
  const float* rvw    = (const float*)d_in[19];
  const float* rvb    = (const float*)d_in[20];
  const float* rvbg   = (const float*)d_in[21];
  const float* rvbb   = (const float*)d_in[22];
  const float* rvbm   = (const float*)d_in[23];
  const float* rvbv   = (const float*)d_in[24];
  const float* fusw   = (const float*)d_in[25];
  const float* fusb   = (const float*)d_in[26];
  const float* fcw    = (const float*)d_in[29];
  const float* fcb    = (const float*)d_in[30];
  const float* sfw    = (const float*)d_in[31];
  const float* sfb    = (const float*)d_in[32];
  const float* sbg    = (const float*)d_in[33];
  const float* sbb    = (const float*)d_in[34];
  const float* sbm    = (const float*)d_in[35];
  const float* sbv    = (const float*)d_in[36];
  const float* finw   = (const float*)d_in[37];
  const float* finb   = (const float*)d_in[38];
  float* out = (float*)d_out;

  char* ws = (char*)d_ws;
  size_t off = 0;
  float* r   = (float*)(ws + off); off += (size_t)16 * 16 * 4096 * 4;   // 4 MB
  u16*   fwb = (u16*)(ws + off);   off += (size_t)512 * 512 * 2;        // 512 KB
  float* cm  = (float*)(ws + off); off += 65536;
  float* rm  = (float*)(ws + off); off += 65536;
  float* ctx = (float*)(ws + off); off += 1024;
  float* wg  = (float*)(ws + off); off += 1024;
  float* at  = (float*)(ws + off); off += 1024;
  float* hfc = (float*)(ws + off); off += 65536;
  float* vfc = (float*)(ws + off); off += 65536;

  k1_reduce<<<1024, 256, 0, stream>>>(x, red_w, red_b, rbg, rbb, rbm, rbv, r);
  k2_means<<<256, 256, 0, stream>>>(r, cm, rm, ctx);
  k3x<<<273, 256, 0, stream>>>(finw, fwb,
                               ctx, f1w, f1b, lng, lnb, f2w, f2b, fcw, fcb, wg, at,
                               cm, rm, rhw, rhb, rhbg, rhbb, rhbm, rhbv,
                               rvw, rvb, rvbg, rvbb, rvbm, rvbv, fusw, fusb, hfc, vfc);
  k45_v4<<<1024, 512, 0, stream>>>(x, r, wg, at, hfc, vfc,
                                   sfw, sfb, sbg, sbb, sbm, sbv, fwb, finb, out);
}